// Round 2
// baseline (891.658 us; speedup 1.0000x reference)
//
#include <hip/hip_runtime.h>

typedef __attribute__((ext_vector_type(8))) short short8;
typedef __attribute__((ext_vector_type(4))) float f32x4;
typedef unsigned short ushort_t;
typedef unsigned int uint32;

// ---------- constants ----------
#define N0 30000
#define N1 90000
#define N2 60000
#define P0 30208   // 236*128
#define P1 90112   // 704*128
#define P2 60032   // 469*128
#define S1OFF 30208
#define S2OFF 120320
#define MPAD 180352  // P0+P1+P2
#define MT_ALL 1409  // MPAD/128
#define MT0 236
#define MT1 704
#define MT2 469

__device__ __forceinline__ float bf2f(ushort_t u) {
    union { uint32 i; float f; } v; v.i = ((uint32)u) << 16; return v.f;
}
__device__ __forceinline__ ushort_t f2bf(float f) {
    union { float f; uint32 i; } v; v.f = f;
    uint32 x = v.i;
    x += ((x >> 16) & 1u) + 0x7FFFu;   // RNE
    return (ushort_t)(x >> 16);
}

// ---------- prep: weights -> bf16 transposed layouts ----------
__global__ __launch_bounds__(256) void prep_w(const float* __restrict__ W1,
                                              const float* __restrict__ Wagg,
                                              const float* __restrict__ bagg,
                                              ushort_t* __restrict__ W1t,   // [4][128][256]
                                              ushort_t* __restrict__ Wgt,   // [4][3][128][128]
                                              ushort_t* __restrict__ WgtC,  // [128][512]
                                              float* __restrict__ bsum) {   // [128]
    int idx = blockIdx.x * blockDim.x + threadIdx.x;
    if (idx < 131072) {  // W1t[h][n][k] = W1[h][k][n]
        int h = idx >> 15, rem = idx & 32767, n = rem >> 8, k = rem & 255;
        W1t[idx] = f2bf(W1[((size_t)h * 256 + k) * 128 + n]);
    }
    if (idx < 196608) {  // Wgt[h][l][n][k] = Wagg[h][(l+1)*128+k][n]
        int h = idx / 49152, rem = idx % 49152;
        int l = rem / 16384, rem2 = rem % 16384, n = rem2 >> 7, k = rem2 & 127;
        Wgt[idx] = f2bf(Wagg[((size_t)h * 512 + (l + 1) * 128 + k) * 128 + n]);
    }
    if (idx < 65536) {   // WgtC[n][h*128+k] = Wagg[h][k][n]  (block 0)
        int n = idx >> 9, kk = idx & 511, h = kk >> 7, k = kk & 127;
        WgtC[idx] = f2bf(Wagg[((size_t)h * 512 + k) * 128 + n]);
    }
    if (idx < 128) {
        float s = 0.f;
        #pragma unroll
        for (int h = 0; h < 4; ++h) s += bagg[h * 128 + idx];
        bsum[idx] = s;
    }
}

// ---------- linear1 for all 4 heads, A-tile resident in LDS ----------
// Y[MPAD][512] = relu(x @ W1_h + b1_h) for h=0..3 (col block h*128)
__global__ __launch_bounds__(256) void gemm_x(const float* __restrict__ x0,
                                              const float* __restrict__ x1,
                                              const float* __restrict__ x2,
                                              const ushort_t* __restrict__ W1t,
                                              const float* __restrict__ b1,
                                              ushort_t* __restrict__ Y) {
    __shared__ ushort_t As[128 * 264];  // 128 rows x 256 k (+8 pad)
    __shared__ ushort_t Bs[128 * 40];   // 128 n x 32 k (+8 pad)
    const int tid = threadIdx.x;
    const int lane = tid & 63;
    const int wid = tid >> 6;
    const int wm = wid >> 1, wn = wid & 1;
    const int l15 = lane & 15, lg = lane >> 4;
    const int r0 = blockIdx.x * 128;

    const float* src; int jbase, nreal;
    if (r0 < P0)          { src = x0; jbase = r0;         nreal = N0; }
    else if (r0 < S2OFF)  { src = x1; jbase = r0 - S1OFF; nreal = N1; }
    else                  { src = x2; jbase = r0 - S2OFF; nreal = N2; }

    // stage A once: f32 -> bf16
    for (int c = 0; c < 32; ++c) {
        int f = tid + c * 256;          // float4 index
        int row = f >> 6, col4 = f & 63;
        int j = jbase + row;
        float vx = 0.f, vy = 0.f, vz = 0.f, vw = 0.f;
        if (j < nreal) {
            const float4 v = *(const float4*)(src + (size_t)j * 256 + col4 * 4);
            vx = v.x; vy = v.y; vz = v.z; vw = v.w;
        }
        ushort_t o[4] __attribute__((aligned(8)));
        o[0] = f2bf(vx); o[1] = f2bf(vy); o[2] = f2bf(vz); o[3] = f2bf(vw);
        *(uint2*)(As + row * 264 + col4 * 4) = *(const uint2*)o;
    }
    __syncthreads();

    for (int h = 0; h < 4; ++h) {
        f32x4 acc[4][4] = {};
        const ushort_t* Bh = W1t + h * 32768;
        for (int kt = 0; kt < 256; kt += 32) {
            #pragma unroll
            for (int u = 0; u < 2; ++u) {
                int g = tid * 2 + u;
                int n = g >> 2, kc = g & 3;
                *(uint4*)(Bs + n * 40 + kc * 8) = *(const uint4*)(Bh + n * 256 + kt + kc * 8);
            }
            __syncthreads();
            short8 af[4], bfr[4];
            #pragma unroll
            for (int m = 0; m < 4; ++m)
                af[m] = *(const short8*)(As + (wm * 64 + m * 16 + l15) * 264 + kt + lg * 8);
            #pragma unroll
            for (int n = 0; n < 4; ++n)
                bfr[n] = *(const short8*)(Bs + (wn * 64 + n * 16 + l15) * 40 + lg * 8);
            #pragma unroll
            for (int m = 0; m < 4; ++m)
                #pragma unroll
                for (int n = 0; n < 4; ++n)
                    acc[m][n] = __builtin_amdgcn_mfma_f32_16x16x32_bf16(af[m], bfr[n], acc[m][n], 0, 0, 0);
            __syncthreads();
        }
        #pragma unroll
        for (int n = 0; n < 4; ++n) {
            int col = wn * 64 + n * 16 + l15;
            float bb = b1[h * 128 + col];
            #pragma unroll
            for (int m = 0; m < 4; ++m)
            #pragma unroll
            for (int j = 0; j < 4; ++j) {
                int row = r0 + wm * 64 + m * 16 + lg * 4 + j;
                float v = acc[m][n][j] + bb;
                v = v > 0.f ? v : 0.f;
                Y[(size_t)row * 512 + h * 128 + col] = f2bf(v);
            }
        }
    }
}

// ---------- generic MFMA GEMM (bf16 A), 128x128 tile ----------
// EPI 1: v -> bf16 out   (z projection; outBF may alias A -> no restrict)
// EPI 2: 0.25*(v+bias) -> f32 out, row<rowGuard   (out init)
template<int EPI>
__global__ __launch_bounds__(256)
void gemm_k(const ushort_t* A, int ldA, int strideA,
            const ushort_t* __restrict__ B, int K, int strideB,
            ushort_t* outBF, int outLd, int strideOut,
            float* __restrict__ outF,
            const float* __restrict__ bias, int strideBias,
            int rowGuard)
{
    __shared__ ushort_t As[128 * 40];
    __shared__ ushort_t Bs[128 * 40];
    const int tid = threadIdx.x;
    const int lane = tid & 63;
    const int wid = tid >> 6;
    const int wm = wid >> 1, wn = wid & 1;
    const int r0 = blockIdx.x * 128;
    const int l15 = lane & 15, lg = lane >> 4;

    A += (size_t)blockIdx.y * strideA;
    B += (size_t)blockIdx.y * strideB;
    if (outBF) outBF += (size_t)blockIdx.y * strideOut;
    if (bias) bias += (size_t)blockIdx.y * strideBias;

    f32x4 acc[4][4] = {};

    for (int kt = 0; kt < K; kt += 32) {
        #pragma unroll
        for (int c = 0; c < 2; ++c) {
            int idx = tid + c * 256;
            int row = idx >> 2, kc = idx & 3;
            uint4 va = *(const uint4*)(A + (size_t)(r0 + row) * ldA + kt + kc * 8);
            *(uint4*)(As + row * 40 + kc * 8) = va;
            uint4 vb = *(const uint4*)(B + (size_t)row * K + kt + kc * 8);
            *(uint4*)(Bs + row * 40 + kc * 8) = vb;
        }
        __syncthreads();
        short8 af[4], bfr[4];
        #pragma unroll
        for (int m = 0; m < 4; ++m)
            af[m] = *(const short8*)(As + (wm * 64 + m * 16 + l15) * 40 + lg * 8);
        #pragma unroll
        for (int n = 0; n < 4; ++n)
            bfr[n] = *(const short8*)(Bs + (wn * 64 + n * 16 + l15) * 40 + lg * 8);
        #pragma unroll
        for (int m = 0; m < 4; ++m)
            #pragma unroll
            for (int n = 0; n < 4; ++n)
                acc[m][n] = __builtin_amdgcn_mfma_f32_16x16x32_bf16(af[m], bfr[n], acc[m][n], 0, 0, 0);
        __syncthreads();
    }

    #pragma unroll
    for (int m = 0; m < 4; ++m)
    #pragma unroll
    for (int n = 0; n < 4; ++n)
    #pragma unroll
    for (int j = 0; j < 4; ++j) {
        int row = r0 + wm * 64 + m * 16 + lg * 4 + j;
        int col = wn * 64 + n * 16 + l15;
        float v = acc[m][n][j];
        if (EPI == 1) {
            outBF[(size_t)row * outLd + col] = f2bf(v);
        } else {
            if (row < rowGuard) outF[(size_t)row * 128 + col] = 0.25f * (v + bias[col]);
        }
    }
}

// ---------- attention coefficients ----------
__global__ __launch_bounds__(256) void attn_coef(const ushort_t* __restrict__ Y,
                                                 const float* __restrict__ a1w,
                                                 const float* __restrict__ a1b,
                                                 const float* __restrict__ a2w,
                                                 const float* __restrict__ a2b,
                                                 float* __restrict__ a1o,   // [4][P0]
                                                 float* __restrict__ a2o) { // [4][MPAD]
    int tid = threadIdx.x, lane = tid & 63, wid = tid >> 6;
    int R = blockIdx.x * 4 + wid;
    int h = lane >> 4, s = lane & 15;
    uint4 v = *(const uint4*)(Y + (size_t)R * 512 + h * 128 + s * 8);
    const ushort_t* u = (const ushort_t*)&v;
    float x[8];
    #pragma unroll
    for (int i = 0; i < 8; ++i) x[i] = bf2f(u[i]);
    float d2 = 0.f;
    #pragma unroll
    for (int i = 0; i < 8; ++i) d2 += x[i] * a2w[h * 128 + s * 8 + i];
    #pragma unroll
    for (int off = 1; off < 16; off <<= 1) d2 += __shfl_xor(d2, off);
    if (s == 0) a2o[(size_t)h * MPAD + R] = d2 + a2b[h];
    if (R < N0) {
        float d1 = 0.f;
        #pragma unroll
        for (int i = 0; i < 8; ++i) d1 += x[i] * a1w[h * 128 + s * 8 + i];
        #pragma unroll
        for (int off = 1; off < 16; off <<= 1) d1 += __shfl_xor(d1, off);
        if (s == 0) a1o[(size_t)h * P0 + R] = d1 + a1b[h];
    }
}

// ---------- edge scatter: out[r] += 0.25 * sum_h att_h * z_h[c] ----------
template<int EPB>
__global__ __launch_bounds__(256) void edge_agg(const int* __restrict__ rows,
                                                const int* __restrict__ cols,
                                                int nE, int Sl,
                                                const float* __restrict__ a1,
                                                const float* __restrict__ a2,
                                                const ushort_t* __restrict__ z,
                                                float* __restrict__ out) {
    int d = threadIdx.x & 127;
    int sub = threadIdx.x >> 7;
    int e0 = blockIdx.x * EPB + sub;
    for (int i = 0; i < EPB; i += 2) {
        int e = e0 + i;
        if (e < nE) {
            int r = rows[e];
            int cg = Sl + cols[e];
            float acc = 0.f;
            #pragma unroll
            for (int h = 0; h < 4; ++h) {
                float s = a1[h * P0 + r] + a2[h * MPAD + cg];
                float att = 0.25f / (1.f + __expf(-s));
                acc += att * bf2f(z[(size_t)cg * 512 + h * 128 + d]);
            }
            atomicAdd(out + (size_t)r * 128 + d, acc);
        }
    }
}

extern "C" void kernel_launch(void* const* d_in, const int* in_sizes, int n_in,
                              void* d_out, int out_size, void* d_ws, size_t ws_size,
                              hipStream_t stream) {
    const float* x0   = (const float*)d_in[0];
    const float* x1   = (const float*)d_in[1];
    const float* x2   = (const float*)d_in[2];
    const int* rows0  = (const int*)d_in[3];
    const int* cols0  = (const int*)d_in[4];
    const int* rows1  = (const int*)d_in[5];
    const int* cols1  = (const int*)d_in[6];
    const int* rows2  = (const int*)d_in[7];
    const int* cols2  = (const int*)d_in[8];
    const float* W1   = (const float*)d_in[9];
    const float* b1   = (const float*)d_in[10];
    const float* a1w  = (const float*)d_in[11];
    const float* a1b  = (const float*)d_in[12];
    const float* a2w  = (const float*)d_in[13];
    const float* a2b  = (const float*)d_in[14];
    const float* Wagg = (const float*)d_in[15];
    const float* bagg = (const float*)d_in[16];
    float* out = (float*)d_out;
    char* ws = (char*)d_ws;

    // workspace layout — total 188,836,352 B (z overwrites Y in place)
    ushort_t* Y    = (ushort_t*)(ws);                 // [MPAD][512] bf16 = 184,680,448
    float*    a1o  = (float*)(ws + 184680448);        // [4][P0]   483,328
    float*    a2o  = (float*)(ws + 185163776);        // [4][MPAD] 2,885,632
    ushort_t* W1t  = (ushort_t*)(ws + 188049408);     // [4][128][256] 262,144
    ushort_t* Wgt  = (ushort_t*)(ws + 188311552);     // [4][3][128][128] 393,216
    ushort_t* WgtC = (ushort_t*)(ws + 188704768);     // [128][512] 131,072
    float*    bsum = (float*)(ws + 188835840);        // [128] 512

    // 1) weight prep
    prep_w<<<768, 256, 0, stream>>>(W1, Wagg, bagg, W1t, Wgt, WgtC, bsum);

    // 2) Y = relu(x @ W1 + b1), all heads, X read once (f32 -> bf16 in-kernel)
    gemm_x<<<MT_ALL, 256, 0, stream>>>(x0, x1, x2, W1t, b1, Y);

    // 3) attention coefficients (reads Y)
    attn_coef<<<MPAD / 4, 256, 0, stream>>>(Y, a1w, a1b, a2w, a2b, a1o, a2o);

    // 4) out init = 0.25*(Y0_allheads @ WgtC + bsum)  (reads Y level 0)
    gemm_k<2><<<dim3(MT0, 1), 256, 0, stream>>>(
        Y, 512, 0, WgtC, 512, 0, nullptr, 0, 0, out, bsum, 0, N0);

    // 5) z = Y_h @ Wg_{l+1,h}  IN PLACE on Y (after all Y readers above)
    gemm_k<1><<<dim3(MT0, 4), 256, 0, stream>>>(
        Y, 512, 128, Wgt + 0 * 16384, 128, 3 * 16384, Y, 512, 128, nullptr, nullptr, 0, 0);
    gemm_k<1><<<dim3(MT1, 4), 256, 0, stream>>>(
        Y + (size_t)S1OFF * 512, 512, 128, Wgt + 1 * 16384, 128, 3 * 16384,
        Y + (size_t)S1OFF * 512, 512, 128, nullptr, nullptr, 0, 0);
    gemm_k<1><<<dim3(MT2, 4), 256, 0, stream>>>(
        Y + (size_t)S2OFF * 512, 512, 128, Wgt + 2 * 16384, 128, 3 * 16384,
        Y + (size_t)S2OFF * 512, 512, 128, nullptr, nullptr, 0, 0);

    // 6) edge scatter (z == Y buffer now holds projections)
    edge_agg<16><<<960000 / 16, 256, 0, stream>>>(rows0, cols0, 960000, 0,     a1o, a2o, Y, out);
    edge_agg<16><<<180000 / 16, 256, 0, stream>>>(rows1, cols1, 180000, S1OFF, a1o, a2o, Y, out);
    edge_agg<16><<<180000 / 16, 256, 0, stream>>>(rows2, cols2, 180000, S2OFF, a1o, a2o, Y, out);
}

// Round 3
// 699.279 us; speedup vs baseline: 1.2751x; 1.2751x over previous
//
#include <hip/hip_runtime.h>

typedef __attribute__((ext_vector_type(8))) short short8;
typedef __attribute__((ext_vector_type(4))) float f32x4;
typedef unsigned short ushort_t;
typedef unsigned int uint32;

// ---------- constants ----------
#define N0 30000
#define N1 90000
#define N2 60000
#define P0 30208   // 236*128
#define P1 90112   // 704*128
#define P2 60032   // 469*128
#define S1OFF 30208
#define S2OFF 120320
#define MPAD 180352  // P0+P1+P2
#define MT_ALL 1409  // MPAD/128
#define MT0 236
#define MT1 704
#define MT2 469
#define NNZ_ALL 1320000

__device__ __forceinline__ float bf2f(ushort_t u) {
    union { uint32 i; float f; } v; v.i = ((uint32)u) << 16; return v.f;
}
__device__ __forceinline__ ushort_t f2bf(float f) {
    union { float f; uint32 i; } v; v.f = f;
    uint32 x = v.i;
    x += ((x >> 16) & 1u) + 0x7FFFu;   // RNE
    return (ushort_t)(x >> 16);
}

// ---------- prep: weights -> bf16 transposed layouts ----------
__global__ __launch_bounds__(256) void prep_w(const float* __restrict__ W1,
                                              const float* __restrict__ Wagg,
                                              const float* __restrict__ bagg,
                                              ushort_t* __restrict__ W1t,   // [4][128][256]
                                              ushort_t* __restrict__ Wgt,   // [4][3][128][128]
                                              ushort_t* __restrict__ WgtC,  // [128][512]
                                              float* __restrict__ bsum) {   // [128]
    int idx = blockIdx.x * blockDim.x + threadIdx.x;
    if (idx < 131072) {  // W1t[h][n][k] = W1[h][k][n]
        int h = idx >> 15, rem = idx & 32767, n = rem >> 8, k = rem & 255;
        W1t[idx] = f2bf(W1[((size_t)h * 256 + k) * 128 + n]);
    }
    if (idx < 196608) {  // Wgt[h][l][n][k] = Wagg[h][(l+1)*128+k][n]
        int h = idx / 49152, rem = idx % 49152;
        int l = rem / 16384, rem2 = rem % 16384, n = rem2 >> 7, k = rem2 & 127;
        Wgt[idx] = f2bf(Wagg[((size_t)h * 512 + (l + 1) * 128 + k) * 128 + n]);
    }
    if (idx < 65536) {   // WgtC[n][h*128+k] = Wagg[h][k][n]  (block 0)
        int n = idx >> 9, kk = idx & 511, h = kk >> 7, k = kk & 127;
        WgtC[idx] = f2bf(Wagg[((size_t)h * 512 + k) * 128 + n]);
    }
    if (idx < 128) {
        float s = 0.f;
        #pragma unroll
        for (int h = 0; h < 4; ++h) s += bagg[h * 128 + idx];
        bsum[idx] = s;
    }
}

// ---------- CSR build ----------
__global__ __launch_bounds__(256) void csr_zero(int* __restrict__ cur) {
    int i = blockIdx.x * blockDim.x + threadIdx.x;
    if (i < P0) cur[i] = 0;
}

__global__ __launch_bounds__(256) void csr_hist(const int* __restrict__ rows, int nE,
                                                int* __restrict__ cur) {
    int i = blockIdx.x * blockDim.x + threadIdx.x;
    if (i < nE) atomicAdd(cur + rows[i], 1);
}

// single block, 1024 threads: exclusive scan of cur[0..N0) -> rowPtr & cur
__global__ __launch_bounds__(1024) void csr_scan(int* __restrict__ cur,
                                                 int* __restrict__ rowPtr) {
    __shared__ int ssum[1024];
    const int t = threadIdx.x;
    const int base = t * 30;          // 1024*30 = 30720 >= N0
    int loc[30];
    int s = 0;
    #pragma unroll
    for (int i = 0; i < 30; ++i) {
        int r = base + i;
        int v = (r < N0) ? cur[r] : 0;
        loc[i] = s; s += v;
    }
    ssum[t] = s;
    __syncthreads();
    for (int off = 1; off < 1024; off <<= 1) {
        int v = (t >= off) ? ssum[t - off] : 0;
        __syncthreads();
        ssum[t] += v;
        __syncthreads();
    }
    int carry = (t == 0) ? 0 : ssum[t - 1];
    #pragma unroll
    for (int i = 0; i < 30; ++i) {
        int r = base + i;
        if (r < N0) {
            int p = carry + loc[i];
            rowPtr[r] = p;
            cur[r] = p;
        }
    }
    if (t == 0) rowPtr[N0] = NNZ_ALL;
}

__global__ __launch_bounds__(256) void csr_scatter(const int* __restrict__ rows,
                                                   const int* __restrict__ cols,
                                                   int nE, int Sl,
                                                   int* __restrict__ cur,
                                                   int* __restrict__ sortedCg) {
    int i = blockIdx.x * blockDim.x + threadIdx.x;
    if (i < nE) {
        int pos = atomicAdd(cur + rows[i], 1);
        sortedCg[pos] = Sl + cols[i];
    }
}

// ---------- linear1 for all 4 heads, A-tile resident in LDS ----------
__global__ __launch_bounds__(256) void gemm_x(const float* __restrict__ x0,
                                              const float* __restrict__ x1,
                                              const float* __restrict__ x2,
                                              const ushort_t* __restrict__ W1t,
                                              const float* __restrict__ b1,
                                              ushort_t* __restrict__ Y) {
    __shared__ ushort_t As[128 * 264];  // 128 rows x 256 k (+8 pad)
    __shared__ ushort_t Bs[128 * 40];   // 128 n x 32 k (+8 pad)
    const int tid = threadIdx.x;
    const int lane = tid & 63;
    const int wid = tid >> 6;
    const int wm = wid >> 1, wn = wid & 1;
    const int l15 = lane & 15, lg = lane >> 4;
    const int r0 = blockIdx.x * 128;

    const float* src; int jbase, nreal;
    if (r0 < P0)          { src = x0; jbase = r0;         nreal = N0; }
    else if (r0 < S2OFF)  { src = x1; jbase = r0 - S1OFF; nreal = N1; }
    else                  { src = x2; jbase = r0 - S2OFF; nreal = N2; }

    for (int c = 0; c < 32; ++c) {
        int f = tid + c * 256;
        int row = f >> 6, col4 = f & 63;
        int j = jbase + row;
        float vx = 0.f, vy = 0.f, vz = 0.f, vw = 0.f;
        if (j < nreal) {
            const float4 v = *(const float4*)(src + (size_t)j * 256 + col4 * 4);
            vx = v.x; vy = v.y; vz = v.z; vw = v.w;
        }
        ushort_t o[4] __attribute__((aligned(8)));
        o[0] = f2bf(vx); o[1] = f2bf(vy); o[2] = f2bf(vz); o[3] = f2bf(vw);
        *(uint2*)(As + row * 264 + col4 * 4) = *(const uint2*)o;
    }
    __syncthreads();

    for (int h = 0; h < 4; ++h) {
        f32x4 acc[4][4] = {};
        const ushort_t* Bh = W1t + h * 32768;
        for (int kt = 0; kt < 256; kt += 32) {
            #pragma unroll
            for (int u = 0; u < 2; ++u) {
                int g = tid * 2 + u;
                int n = g >> 2, kc = g & 3;
                *(uint4*)(Bs + n * 40 + kc * 8) = *(const uint4*)(Bh + n * 256 + kt + kc * 8);
            }
            __syncthreads();
            short8 af[4], bfr[4];
            #pragma unroll
            for (int m = 0; m < 4; ++m)
                af[m] = *(const short8*)(As + (wm * 64 + m * 16 + l15) * 264 + kt + lg * 8);
            #pragma unroll
            for (int n = 0; n < 4; ++n)
                bfr[n] = *(const short8*)(Bs + (wn * 64 + n * 16 + l15) * 40 + lg * 8);
            #pragma unroll
            for (int m = 0; m < 4; ++m)
                #pragma unroll
                for (int n = 0; n < 4; ++n)
                    acc[m][n] = __builtin_amdgcn_mfma_f32_16x16x32_bf16(af[m], bfr[n], acc[m][n], 0, 0, 0);
            __syncthreads();
        }
        #pragma unroll
        for (int n = 0; n < 4; ++n) {
            int col = wn * 64 + n * 16 + l15;
            float bb = b1[h * 128 + col];
            #pragma unroll
            for (int m = 0; m < 4; ++m)
            #pragma unroll
            for (int j = 0; j < 4; ++j) {
                int row = r0 + wm * 64 + m * 16 + lg * 4 + j;
                float v = acc[m][n][j] + bb;
                v = v > 0.f ? v : 0.f;
                Y[(size_t)row * 512 + h * 128 + col] = f2bf(v);
            }
        }
    }
}

// ---------- generic MFMA GEMM (bf16 A), 128x128 tile ----------
template<int EPI>
__global__ __launch_bounds__(256)
void gemm_k(const ushort_t* A, int ldA, int strideA,
            const ushort_t* __restrict__ B, int K, int strideB,
            ushort_t* outBF, int outLd, int strideOut,
            float* __restrict__ outF,
            const float* __restrict__ bias, int strideBias,
            int rowGuard)
{
    __shared__ ushort_t As[128 * 40];
    __shared__ ushort_t Bs[128 * 40];
    const int tid = threadIdx.x;
    const int lane = tid & 63;
    const int wid = tid >> 6;
    const int wm = wid >> 1, wn = wid & 1;
    const int r0 = blockIdx.x * 128;
    const int l15 = lane & 15, lg = lane >> 4;

    A += (size_t)blockIdx.y * strideA;
    B += (size_t)blockIdx.y * strideB;
    if (outBF) outBF += (size_t)blockIdx.y * strideOut;
    if (bias) bias += (size_t)blockIdx.y * strideBias;

    f32x4 acc[4][4] = {};

    for (int kt = 0; kt < K; kt += 32) {
        #pragma unroll
        for (int c = 0; c < 2; ++c) {
            int idx = tid + c * 256;
            int row = idx >> 2, kc = idx & 3;
            uint4 va = *(const uint4*)(A + (size_t)(r0 + row) * ldA + kt + kc * 8);
            *(uint4*)(As + row * 40 + kc * 8) = va;
            uint4 vb = *(const uint4*)(B + (size_t)row * K + kt + kc * 8);
            *(uint4*)(Bs + row * 40 + kc * 8) = vb;
        }
        __syncthreads();
        short8 af[4], bfr[4];
        #pragma unroll
        for (int m = 0; m < 4; ++m)
            af[m] = *(const short8*)(As + (wm * 64 + m * 16 + l15) * 40 + lg * 8);
        #pragma unroll
        for (int n = 0; n < 4; ++n)
            bfr[n] = *(const short8*)(Bs + (wn * 64 + n * 16 + l15) * 40 + lg * 8);
        #pragma unroll
        for (int m = 0; m < 4; ++m)
            #pragma unroll
            for (int n = 0; n < 4; ++n)
                acc[m][n] = __builtin_amdgcn_mfma_f32_16x16x32_bf16(af[m], bfr[n], acc[m][n], 0, 0, 0);
        __syncthreads();
    }

    #pragma unroll
    for (int m = 0; m < 4; ++m)
    #pragma unroll
    for (int n = 0; n < 4; ++n)
    #pragma unroll
    for (int j = 0; j < 4; ++j) {
        int row = r0 + wm * 64 + m * 16 + lg * 4 + j;
        int col = wn * 64 + n * 16 + l15;
        float v = acc[m][n][j];
        if (EPI == 1) {
            outBF[(size_t)row * outLd + col] = f2bf(v);
        } else {
            if (row < rowGuard) outF[(size_t)row * 128 + col] = 0.25f * (v + bias[col]);
        }
    }
}

// ---------- attention coefficients ----------
__global__ __launch_bounds__(256) void attn_coef(const ushort_t* __restrict__ Y,
                                                 const float* __restrict__ a1w,
                                                 const float* __restrict__ a1b,
                                                 const float* __restrict__ a2w,
                                                 const float* __restrict__ a2b,
                                                 float* __restrict__ a1o,   // [4][P0]
                                                 float* __restrict__ a2o) { // [4][MPAD]
    int tid = threadIdx.x, lane = tid & 63, wid = tid >> 6;
    int R = blockIdx.x * 4 + wid;
    int h = lane >> 4, s = lane & 15;
    uint4 v = *(const uint4*)(Y + (size_t)R * 512 + h * 128 + s * 8);
    const ushort_t* u = (const ushort_t*)&v;
    float x[8];
    #pragma unroll
    for (int i = 0; i < 8; ++i) x[i] = bf2f(u[i]);
    float d2 = 0.f;
    #pragma unroll
    for (int i = 0; i < 8; ++i) d2 += x[i] * a2w[h * 128 + s * 8 + i];
    #pragma unroll
    for (int off = 1; off < 16; off <<= 1) d2 += __shfl_xor(d2, off);
    if (s == 0) a2o[(size_t)h * MPAD + R] = d2 + a2b[h];
    if (R < N0) {
        float d1 = 0.f;
        #pragma unroll
        for (int i = 0; i < 8; ++i) d1 += x[i] * a1w[h * 128 + s * 8 + i];
        #pragma unroll
        for (int off = 1; off < 16; off <<= 1) d1 += __shfl_xor(d1, off);
        if (s == 0) a1o[(size_t)h * P0 + R] = d1 + a1b[h];
    }
}

// ---------- pull aggregation: one wave per output row, no atomics ----------
__global__ __launch_bounds__(256) void pull_agg(const int* __restrict__ rowPtr,
                                                const int* __restrict__ sortedCg,
                                                const float* __restrict__ a1,
                                                const float* __restrict__ a2,
                                                const ushort_t* __restrict__ z,
                                                float* __restrict__ out) {
    int w = blockIdx.x * 4 + (threadIdx.x >> 6);
    if (w >= N0) return;
    const int lane = threadIdx.x & 63;
    const int h = lane >> 4, g = lane & 15;

    const float a1r = a1[(size_t)h * P0 + w];
    const float* a2h = a2 + (size_t)h * MPAD;
    int beg = rowPtr[w], end = rowPtr[w + 1];

    float acc[8] = {0.f, 0.f, 0.f, 0.f, 0.f, 0.f, 0.f, 0.f};
    for (int e = beg; e < end; ++e) {
        int cg = sortedCg[e];
        float s = a1r + a2h[cg];
        float att = 0.25f / (1.f + __expf(-s));
        uint4 v = *(const uint4*)(z + (size_t)cg * 512 + lane * 8);  // lane*8 = h*128 + g*8
        const ushort_t* u = (const ushort_t*)&v;
        #pragma unroll
        for (int j = 0; j < 8; ++j) acc[j] += att * bf2f(u[j]);
    }
    // sum over heads: lanes differing in bits 4,5 share dim-block g
    #pragma unroll
    for (int j = 0; j < 8; ++j) {
        acc[j] += __shfl_xor(acc[j], 16);
        acc[j] += __shfl_xor(acc[j], 32);
    }
    // each lane writes 2 of the 8 dims of block g (disjoint across h)
    float2* p = (float2*)(out + (size_t)w * 128 + g * 8 + h * 2);
    float2 o = *p;
    o.x += acc[h * 2 + 0];
    o.y += acc[h * 2 + 1];
    *p = o;
}

extern "C" void kernel_launch(void* const* d_in, const int* in_sizes, int n_in,
                              void* d_out, int out_size, void* d_ws, size_t ws_size,
                              hipStream_t stream) {
    const float* x0   = (const float*)d_in[0];
    const float* x1   = (const float*)d_in[1];
    const float* x2   = (const float*)d_in[2];
    const int* rows0  = (const int*)d_in[3];
    const int* cols0  = (const int*)d_in[4];
    const int* rows1  = (const int*)d_in[5];
    const int* cols1  = (const int*)d_in[6];
    const int* rows2  = (const int*)d_in[7];
    const int* cols2  = (const int*)d_in[8];
    const float* W1   = (const float*)d_in[9];
    const float* b1   = (const float*)d_in[10];
    const float* a1w  = (const float*)d_in[11];
    const float* a1b  = (const float*)d_in[12];
    const float* a2w  = (const float*)d_in[13];
    const float* a2b  = (const float*)d_in[14];
    const float* Wagg = (const float*)d_in[15];
    const float* bagg = (const float*)d_in[16];
    float* out = (float*)d_out;
    char* ws = (char*)d_ws;

    // workspace layout — total 194,358,016 B
    ushort_t* Y      = (ushort_t*)(ws);               // [MPAD][512] bf16 = 184,680,448
    float*    a1o    = (float*)(ws + 184680448);      // [4][P0]   483,328
    float*    a2o    = (float*)(ws + 185163776);      // [4][MPAD] 2,885,632
    ushort_t* W1t    = (ushort_t*)(ws + 188049408);   // 262,144
    ushort_t* Wgt    = (ushort_t*)(ws + 188311552);   // 393,216
    ushort_t* WgtC   = (ushort_t*)(ws + 188704768);   // 131,072
    float*    bsum   = (float*)(ws + 188835840);      // 512
    int*      cur    = (int*)(ws + 188836352);        // [P0] 120,832
    int*      rowPtr = (int*)(ws + 188957184);        // [P0] 120,832 (needs N0+1)
    int*      srtCg  = (int*)(ws + 189078016);        // [NNZ_ALL] 5,280,000

    // 1) CSR build (independent of GEMM chain)
    csr_zero<<<(P0 + 255) / 256, 256, 0, stream>>>(cur);
    csr_hist<<<(960000 + 255) / 256, 256, 0, stream>>>(rows0, 960000, cur);
    csr_hist<<<(180000 + 255) / 256, 256, 0, stream>>>(rows1, 180000, cur);
    csr_hist<<<(180000 + 255) / 256, 256, 0, stream>>>(rows2, 180000, cur);
    csr_scan<<<1, 1024, 0, stream>>>(cur, rowPtr);
    csr_scatter<<<(960000 + 255) / 256, 256, 0, stream>>>(rows0, cols0, 960000, 0, cur, srtCg);
    csr_scatter<<<(180000 + 255) / 256, 256, 0, stream>>>(rows1, cols1, 180000, S1OFF, cur, srtCg);
    csr_scatter<<<(180000 + 255) / 256, 256, 0, stream>>>(rows2, cols2, 180000, S2OFF, cur, srtCg);

    // 2) weight prep + Y = relu(x @ W1 + b1)
    prep_w<<<768, 256, 0, stream>>>(W1, Wagg, bagg, W1t, Wgt, WgtC, bsum);
    gemm_x<<<MT_ALL, 256, 0, stream>>>(x0, x1, x2, W1t, b1, Y);

    // 3) attention coefficients (reads Y)
    attn_coef<<<MPAD / 4, 256, 0, stream>>>(Y, a1w, a1b, a2w, a2b, a1o, a2o);

    // 4) out init = 0.25*(Y0_allheads @ WgtC + bsum)  (reads Y level 0)
    gemm_k<2><<<dim3(MT0, 1), 256, 0, stream>>>(
        Y, 512, 0, WgtC, 512, 0, nullptr, 0, 0, out, bsum, 0, N0);

    // 5) z = Y_h @ Wg_{l+1,h}  IN PLACE on Y (after all Y readers above)
    gemm_k<1><<<dim3(MT0, 4), 256, 0, stream>>>(
        Y, 512, 128, Wgt + 0 * 16384, 128, 3 * 16384, Y, 512, 128, nullptr, nullptr, 0, 0);
    gemm_k<1><<<dim3(MT1, 4), 256, 0, stream>>>(
        Y + (size_t)S1OFF * 512, 512, 128, Wgt + 1 * 16384, 128, 3 * 16384,
        Y + (size_t)S1OFF * 512, 512, 128, nullptr, nullptr, 0, 0);
    gemm_k<1><<<dim3(MT2, 4), 256, 0, stream>>>(
        Y + (size_t)S2OFF * 512, 512, 128, Wgt + 2 * 16384, 128, 3 * 16384,
        Y + (size_t)S2OFF * 512, 512, 128, nullptr, nullptr, 0, 0);

    // 6) pull aggregation (no atomics; adds to GEMM-initialized out)
    pull_agg<<<(N0 + 3) / 4, 256, 0, stream>>>(rowPtr, srtCg, a1o, a2o, Y, out);
}

// Round 4
// 645.124 us; speedup vs baseline: 1.3822x; 1.0839x over previous
//
#include <hip/hip_runtime.h>

typedef __attribute__((ext_vector_type(8))) short short8;
typedef __attribute__((ext_vector_type(4))) float f32x4;
typedef unsigned short ushort_t;
typedef unsigned int uint32;

// ---------- constants ----------
#define N0 30000
#define N1 90000
#define N2 60000
#define P0 30208   // 236*128
#define S1OFF 30208
#define S2OFF 120320
#define MPAD 180352  // P0+P1+P2
#define MT_ALL 1409  // MPAD/128
#define MT0 236
#define NE0 960000
#define NE1 180000
#define NE2 180000
#define CSTRIDE 30720  // per-level cur/rowPtr stride (>= N0+1)

__device__ __forceinline__ float bf2f(ushort_t u) {
    union { uint32 i; float f; } v; v.i = ((uint32)u) << 16; return v.f;
}
__device__ __forceinline__ ushort_t f2bf(float f) {
    union { float f; uint32 i; } v; v.f = f;
    uint32 x = v.i;
    x += ((x >> 16) & 1u) + 0x7FFFu;   // RNE
    return (ushort_t)(x >> 16);
}

// ---------- prep: weights -> bf16 transposed layouts ----------
__global__ __launch_bounds__(256) void prep_w(const float* __restrict__ W1,
                                              const float* __restrict__ Wagg,
                                              const float* __restrict__ bagg,
                                              ushort_t* __restrict__ W1t,   // [4][128][256]
                                              ushort_t* __restrict__ Wgt,   // [4][3][128][128]
                                              ushort_t* __restrict__ WgtC,  // [128][512]
                                              float* __restrict__ bsum) {   // [128]
    int idx = blockIdx.x * blockDim.x + threadIdx.x;
    if (idx < 131072) {  // W1t[h][n][k] = W1[h][k][n]
        int h = idx >> 15, rem = idx & 32767, n = rem >> 8, k = rem & 255;
        W1t[idx] = f2bf(W1[((size_t)h * 256 + k) * 128 + n]);
    }
    if (idx < 196608) {  // Wgt[h][l][n][k] = Wagg[h][(l+1)*128+k][n]
        int h = idx / 49152, rem = idx % 49152;
        int l = rem / 16384, rem2 = rem % 16384, n = rem2 >> 7, k = rem2 & 127;
        Wgt[idx] = f2bf(Wagg[((size_t)h * 512 + (l + 1) * 128 + k) * 128 + n]);
    }
    if (idx < 65536) {   // WgtC[n][h*128+k] = Wagg[h][k][n]  (block 0)
        int n = idx >> 9, kk = idx & 511, h = kk >> 7, k = kk & 127;
        WgtC[idx] = f2bf(Wagg[((size_t)h * 512 + k) * 128 + n]);
    }
    if (idx < 128) {
        float s = 0.f;
        #pragma unroll
        for (int h = 0; h < 4; ++h) s += bagg[h * 128 + idx];
        bsum[idx] = s;
    }
}

// ---------- CSR build (per level) ----------
__global__ __launch_bounds__(256) void csr_zero(int* __restrict__ cur) {
    int i = blockIdx.x * blockDim.x + threadIdx.x;
    if (i < 3 * CSTRIDE) cur[i] = 0;
}

__global__ __launch_bounds__(256) void csr_hist(const int* __restrict__ rows, int nE,
                                                int* __restrict__ cur) {
    int i = blockIdx.x * blockDim.x + threadIdx.x;
    if (i < nE) atomicAdd(cur + rows[i], 1);
}

// 3 blocks, one per level: exclusive scan of cur -> rowPtr & cur
__global__ __launch_bounds__(1024) void csr_scan(int* __restrict__ curA,
                                                 int* __restrict__ rowPtrA,
                                                 int nE0, int nE1, int nE2) {
    __shared__ int ssum[1024];
    const int b = blockIdx.x;
    int* cur = curA + b * CSTRIDE;
    int* rowPtr = rowPtrA + b * CSTRIDE;
    const int nE = (b == 0) ? nE0 : (b == 1 ? nE1 : nE2);
    const int t = threadIdx.x;
    const int base = t * 30;          // 1024*30 = 30720 >= N0
    int loc[30];
    int s = 0;
    #pragma unroll
    for (int i = 0; i < 30; ++i) {
        int r = base + i;
        int v = (r < N0) ? cur[r] : 0;
        loc[i] = s; s += v;
    }
    ssum[t] = s;
    __syncthreads();
    for (int off = 1; off < 1024; off <<= 1) {
        int v = (t >= off) ? ssum[t - off] : 0;
        __syncthreads();
        ssum[t] += v;
        __syncthreads();
    }
    int carry = (t == 0) ? 0 : ssum[t - 1];
    #pragma unroll
    for (int i = 0; i < 30; ++i) {
        int r = base + i;
        if (r < N0) {
            int p = carry + loc[i];
            rowPtr[r] = p;
            cur[r] = p;
        }
    }
    if (t == 0) rowPtr[N0] = nE;
}

__global__ __launch_bounds__(256) void csr_scatter(const int* __restrict__ rows,
                                                   const int* __restrict__ cols,
                                                   int nE, int Sl,
                                                   int* __restrict__ cur,
                                                   int* __restrict__ sortedCg) {
    int i = blockIdx.x * blockDim.x + threadIdx.x;
    if (i < nE) {
        int pos = atomicAdd(cur + rows[i], 1);
        sortedCg[pos] = Sl + cols[i];
    }
}

// ---------- linear1 for all 4 heads, A-tile resident in LDS ----------
__global__ __launch_bounds__(256) void gemm_x(const float* __restrict__ x0,
                                              const float* __restrict__ x1,
                                              const float* __restrict__ x2,
                                              const ushort_t* __restrict__ W1t,
                                              const float* __restrict__ b1,
                                              ushort_t* __restrict__ Y) {
    __shared__ ushort_t As[128 * 264];  // 128 rows x 256 k (+8 pad)
    __shared__ ushort_t Bs[128 * 40];   // 128 n x 32 k (+8 pad)
    const int tid = threadIdx.x;
    const int lane = tid & 63;
    const int wid = tid >> 6;
    const int wm = wid >> 1, wn = wid & 1;
    const int l15 = lane & 15, lg = lane >> 4;
    const int r0 = blockIdx.x * 128;

    const float* src; int jbase, nreal;
    if (r0 < P0)          { src = x0; jbase = r0;         nreal = N0; }
    else if (r0 < S2OFF)  { src = x1; jbase = r0 - S1OFF; nreal = N1; }
    else                  { src = x2; jbase = r0 - S2OFF; nreal = N2; }

    for (int c = 0; c < 32; ++c) {
        int f = tid + c * 256;
        int row = f >> 6, col4 = f & 63;
        int j = jbase + row;
        float vx = 0.f, vy = 0.f, vz = 0.f, vw = 0.f;
        if (j < nreal) {
            const float4 v = *(const float4*)(src + (size_t)j * 256 + col4 * 4);
            vx = v.x; vy = v.y; vz = v.z; vw = v.w;
        }
        ushort_t o[4] __attribute__((aligned(8)));
        o[0] = f2bf(vx); o[1] = f2bf(vy); o[2] = f2bf(vz); o[3] = f2bf(vw);
        *(uint2*)(As + row * 264 + col4 * 4) = *(const uint2*)o;
    }
    __syncthreads();

    for (int h = 0; h < 4; ++h) {
        f32x4 acc[4][4] = {};
        const ushort_t* Bh = W1t + h * 32768;
        for (int kt = 0; kt < 256; kt += 32) {
            #pragma unroll
            for (int u = 0; u < 2; ++u) {
                int g = tid * 2 + u;
                int n = g >> 2, kc = g & 3;
                *(uint4*)(Bs + n * 40 + kc * 8) = *(const uint4*)(Bh + n * 256 + kt + kc * 8);
            }
            __syncthreads();
            short8 af[4], bfr[4];
            #pragma unroll
            for (int m = 0; m < 4; ++m)
                af[m] = *(const short8*)(As + (wm * 64 + m * 16 + l15) * 264 + kt + lg * 8);
            #pragma unroll
            for (int n = 0; n < 4; ++n)
                bfr[n] = *(const short8*)(Bs + (wn * 64 + n * 16 + l15) * 40 + lg * 8);
            #pragma unroll
            for (int m = 0; m < 4; ++m)
                #pragma unroll
                for (int n = 0; n < 4; ++n)
                    acc[m][n] = __builtin_amdgcn_mfma_f32_16x16x32_bf16(af[m], bfr[n], acc[m][n], 0, 0, 0);
            __syncthreads();
        }
        #pragma unroll
        for (int n = 0; n < 4; ++n) {
            int col = wn * 64 + n * 16 + l15;
            float bb = b1[h * 128 + col];
            #pragma unroll
            for (int m = 0; m < 4; ++m)
            #pragma unroll
            for (int j = 0; j < 4; ++j) {
                int row = r0 + wm * 64 + m * 16 + lg * 4 + j;
                float v = acc[m][n][j] + bb;
                v = v > 0.f ? v : 0.f;
                Y[(size_t)row * 512 + h * 128 + col] = f2bf(v);
            }
        }
    }
}

// ---------- out-init GEMM: 0.25*(Y0_allheads @ WgtC + bsum) -> f32 out ----------
__global__ __launch_bounds__(256)
void gemm_init(const ushort_t* __restrict__ A,          // Y, ld 512
               const ushort_t* __restrict__ B,          // WgtC [128][512]
               float* __restrict__ outF,
               const float* __restrict__ bias)
{
    __shared__ ushort_t As[128 * 40];
    __shared__ ushort_t Bs[128 * 40];
    const int tid = threadIdx.x;
    const int lane = tid & 63;
    const int wid = tid >> 6;
    const int wm = wid >> 1, wn = wid & 1;
    const int r0 = blockIdx.x * 128;
    const int l15 = lane & 15, lg = lane >> 4;

    f32x4 acc[4][4] = {};

    for (int kt = 0; kt < 512; kt += 32) {
        #pragma unroll
        for (int c = 0; c < 2; ++c) {
            int idx = tid + c * 256;
            int row = idx >> 2, kc = idx & 3;
            uint4 va = *(const uint4*)(A + (size_t)(r0 + row) * 512 + kt + kc * 8);
            *(uint4*)(As + row * 40 + kc * 8) = va;
            uint4 vb = *(const uint4*)(B + (size_t)row * 512 + kt + kc * 8);
            *(uint4*)(Bs + row * 40 + kc * 8) = vb;
        }
        __syncthreads();
        short8 af[4], bfr[4];
        #pragma unroll
        for (int m = 0; m < 4; ++m)
            af[m] = *(const short8*)(As + (wm * 64 + m * 16 + l15) * 40 + lg * 8);
        #pragma unroll
        for (int n = 0; n < 4; ++n)
            bfr[n] = *(const short8*)(Bs + (wn * 64 + n * 16 + l15) * 40 + lg * 8);
        #pragma unroll
        for (int m = 0; m < 4; ++m)
            #pragma unroll
            for (int n = 0; n < 4; ++n)
                acc[m][n] = __builtin_amdgcn_mfma_f32_16x16x32_bf16(af[m], bfr[n], acc[m][n], 0, 0, 0);
        __syncthreads();
    }

    #pragma unroll
    for (int m = 0; m < 4; ++m)
    #pragma unroll
    for (int n = 0; n < 4; ++n)
    #pragma unroll
    for (int j = 0; j < 4; ++j) {
        int row = r0 + wm * 64 + m * 16 + lg * 4 + j;
        int col = wn * 64 + n * 16 + l15;
        if (row < N0) outF[(size_t)row * 128 + col] = 0.25f * (acc[m][n][j] + bias[col]);
    }
}

// ---------- fused z-projection (in place on Y) + attention coefficients ----------
// grid (MT_ALL, 4 heads); K=128 fully staged, one barrier, 64 MFMAs
__global__ __launch_bounds__(256) void gemm_z(const ushort_t* Yin,      // aliases Yout
                                              const ushort_t* __restrict__ Wgt,
                                              const float* __restrict__ a1w,
                                              const float* __restrict__ a1b,
                                              const float* __restrict__ a2w,
                                              const float* __restrict__ a2b,
                                              float* __restrict__ a1o,   // [4][P0]
                                              float* __restrict__ a2o,   // [4][MPAD]
                                              ushort_t* Yout) {
    __shared__ ushort_t As[128 * 136];
    __shared__ ushort_t Bs[128 * 136];
    __shared__ float a1wS[128], a2wS[128];
    const int tid = threadIdx.x;
    const int h = blockIdx.y;
    const int r0 = blockIdx.x * 128;
    const int l = (r0 < P0) ? 0 : (r0 < S2OFF ? 1 : 2);
    const ushort_t* B = Wgt + ((h * 3 + l) << 14);

    if (tid < 128) {
        a1wS[tid] = a1w[h * 128 + tid];
        a2wS[tid] = a2w[h * 128 + tid];
    }
    #pragma unroll
    for (int c = 0; c < 8; ++c) {
        int idx = tid + c * 256;
        int row = idx >> 4, ch = idx & 15;
        *(uint4*)(As + row * 136 + ch * 8) =
            *(const uint4*)(Yin + (size_t)(r0 + row) * 512 + h * 128 + ch * 8);
        *(uint4*)(Bs + row * 136 + ch * 8) = *(const uint4*)(B + row * 128 + ch * 8);
    }
    __syncthreads();

    // attention coefficient dots from the staged Y tile (pre-overwrite values)
    {
        int row = tid >> 1, half = tid & 1;
        const ushort_t* yr = As + row * 136 + half * 64;
        float d1 = 0.f, d2 = 0.f;
        #pragma unroll
        for (int t = 0; t < 8; ++t) {
            short8 v = *(const short8*)(yr + t * 8);
            #pragma unroll
            for (int j = 0; j < 8; ++j) {
                float f = bf2f(((const ushort_t*)&v)[j]);
                d2 += f * a2wS[half * 64 + t * 8 + j];
                d1 += f * a1wS[half * 64 + t * 8 + j];
            }
        }
        d2 += __shfl_xor(d2, 1);
        d1 += __shfl_xor(d1, 1);
        if (half == 0) {
            a2o[(size_t)h * MPAD + r0 + row] = d2 + a2b[h];
            if (l == 0) a1o[(size_t)h * P0 + r0 + row] = d1 + a1b[h];
        }
    }

    const int lane = tid & 63;
    const int wid = tid >> 6;
    const int wm = wid >> 1, wn = wid & 1;
    const int l15 = lane & 15, lg = lane >> 4;

    f32x4 acc[4][4] = {};
    #pragma unroll
    for (int kt = 0; kt < 128; kt += 32) {
        short8 af[4], bfr[4];
        #pragma unroll
        for (int m = 0; m < 4; ++m)
            af[m] = *(const short8*)(As + (wm * 64 + m * 16 + l15) * 136 + kt + lg * 8);
        #pragma unroll
        for (int n = 0; n < 4; ++n)
            bfr[n] = *(const short8*)(Bs + (wn * 64 + n * 16 + l15) * 136 + kt + lg * 8);
        #pragma unroll
        for (int m = 0; m < 4; ++m)
            #pragma unroll
            for (int n = 0; n < 4; ++n)
                acc[m][n] = __builtin_amdgcn_mfma_f32_16x16x32_bf16(af[m], bfr[n], acc[m][n], 0, 0, 0);
    }

    #pragma unroll
    for (int m = 0; m < 4; ++m)
    #pragma unroll
    for (int n = 0; n < 4; ++n)
    #pragma unroll
    for (int j = 0; j < 4; ++j) {
        int row = r0 + wm * 64 + m * 16 + lg * 4 + j;
        int col = wn * 64 + n * 16 + l15;
        Yout[(size_t)row * 512 + h * 128 + col] = f2bf(acc[m][n][j]);
    }
}

// ---------- pull aggregation: one wave per output row, no atomics ----------
__global__ __launch_bounds__(256) void pull_agg(const int* __restrict__ rowPtr,
                                                const int* __restrict__ sortedCg,
                                                const float* __restrict__ a1,
                                                const float* __restrict__ a2,
                                                const ushort_t* __restrict__ z,
                                                float* __restrict__ out) {
    int w = blockIdx.x * 4 + (threadIdx.x >> 6);
    if (w >= N0) return;
    const int lane = threadIdx.x & 63;
    const int h = lane >> 4, g = lane & 15;

    const float a1r = a1[(size_t)h * P0 + w];
    const float* a2h = a2 + (size_t)h * MPAD;
    int beg = rowPtr[w], end = rowPtr[w + 1];

    float acc[8] = {0.f, 0.f, 0.f, 0.f, 0.f, 0.f, 0.f, 0.f};
    int e = beg;
    for (; e + 1 < end; e += 2) {
        int cg0 = sortedCg[e], cg1 = sortedCg[e + 1];
        float s0 = a1r + a2h[cg0];
        float s1 = a1r + a2h[cg1];
        float att0 = 0.25f / (1.f + __expf(-s0));
        float att1 = 0.25f / (1.f + __expf(-s1));
        uint4 v0 = *(const uint4*)(z + (size_t)cg0 * 512 + lane * 8);
        uint4 v1 = *(const uint4*)(z + (size_t)cg1 * 512 + lane * 8);
        const ushort_t* u0 = (const ushort_t*)&v0;
        const ushort_t* u1 = (const ushort_t*)&v1;
        #pragma unroll
        for (int j = 0; j < 8; ++j)
            acc[j] += att0 * bf2f(u0[j]) + att1 * bf2f(u1[j]);
    }
    if (e < end) {
        int cg = sortedCg[e];
        float s = a1r + a2h[cg];
        float att = 0.25f / (1.f + __expf(-s));
        uint4 v = *(const uint4*)(z + (size_t)cg * 512 + lane * 8);
        const ushort_t* u = (const ushort_t*)&v;
        #pragma unroll
        for (int j = 0; j < 8; ++j) acc[j] += att * bf2f(u[j]);
    }
    #pragma unroll
    for (int j = 0; j < 8; ++j) {
        acc[j] += __shfl_xor(acc[j], 16);
        acc[j] += __shfl_xor(acc[j], 32);
    }
    float2* p = (float2*)(out + (size_t)w * 128 + g * 8 + h * 2);
    float2 o = *p;
    o.x += acc[h * 2 + 0];
    o.y += acc[h * 2 + 1];
    *p = o;
}

extern "C" void kernel_launch(void* const* d_in, const int* in_sizes, int n_in,
                              void* d_out, int out_size, void* d_ws, size_t ws_size,
                              hipStream_t stream) {
    const float* x0   = (const float*)d_in[0];
    const float* x1   = (const float*)d_in[1];
    const float* x2   = (const float*)d_in[2];
    const int* rows0  = (const int*)d_in[3];
    const int* cols0  = (const int*)d_in[4];
    const int* rows1  = (const int*)d_in[5];
    const int* cols1  = (const int*)d_in[6];
    const int* rows2  = (const int*)d_in[7];
    const int* cols2  = (const int*)d_in[8];
    const float* W1   = (const float*)d_in[9];
    const float* b1   = (const float*)d_in[10];
    const float* a1w  = (const float*)d_in[11];
    const float* a1b  = (const float*)d_in[12];
    const float* a2w  = (const float*)d_in[13];
    const float* a2b  = (const float*)d_in[14];
    const float* Wagg = (const float*)d_in[15];
    const float* bagg = (const float*)d_in[16];
    float* out = (float*)d_out;
    char* ws = (char*)d_ws;

    // workspace layout — total 194,853,632 B
    ushort_t* Y      = (ushort_t*)(ws);               // [MPAD][512] bf16 = 184,680,448
    float*    a1o    = (float*)(ws + 184680448);      // [4][P0]   483,328
    float*    a2o    = (float*)(ws + 185163776);      // [4][MPAD] 2,885,632
    ushort_t* W1t    = (ushort_t*)(ws + 188049408);   // 262,144
    ushort_t* Wgt    = (ushort_t*)(ws + 188311552);   // 393,216
    ushort_t* WgtC   = (ushort_t*)(ws + 188704768);   // 131,072
    float*    bsum   = (float*)(ws + 188835840);      // 512
    int*      cur    = (int*)(ws + 188836352);        // [3][CSTRIDE] 368,640
    int*      rowPtr = (int*)(ws + 189204992);        // [3][CSTRIDE] 368,640
    int*      srtCg  = (int*)(ws + 189573632);        // [NNZ_ALL] 5,280,000

    int* cur0 = cur,              * cur1 = cur + CSTRIDE,    * cur2 = cur + 2 * CSTRIDE;
    int* rp0  = rowPtr,           * rp1  = rowPtr + CSTRIDE, * rp2  = rowPtr + 2 * CSTRIDE;
    int* srt0 = srtCg,            * srt1 = srtCg + NE0,      * srt2 = srtCg + NE0 + NE1;

    // 1) per-level CSR build (independent of GEMM chain)
    csr_zero<<<(3 * CSTRIDE + 255) / 256, 256, 0, stream>>>(cur);
    csr_hist<<<(NE0 + 255) / 256, 256, 0, stream>>>(rows0, NE0, cur0);
    csr_hist<<<(NE1 + 255) / 256, 256, 0, stream>>>(rows1, NE1, cur1);
    csr_hist<<<(NE2 + 255) / 256, 256, 0, stream>>>(rows2, NE2, cur2);
    csr_scan<<<3, 1024, 0, stream>>>(cur, rowPtr, NE0, NE1, NE2);
    csr_scatter<<<(NE0 + 255) / 256, 256, 0, stream>>>(rows0, cols0, NE0, 0,     cur0, srt0);
    csr_scatter<<<(NE1 + 255) / 256, 256, 0, stream>>>(rows1, cols1, NE1, S1OFF, cur1, srt1);
    csr_scatter<<<(NE2 + 255) / 256, 256, 0, stream>>>(rows2, cols2, NE2, S2OFF, cur2, srt2);

    // 2) weight prep + Y = relu(x @ W1 + b1)
    prep_w<<<768, 256, 0, stream>>>(W1, Wagg, bagg, W1t, Wgt, WgtC, bsum);
    gemm_x<<<MT_ALL, 256, 0, stream>>>(x0, x1, x2, W1t, b1, Y);

    // 3) out init = 0.25*(Y0_allheads @ WgtC + bsum)  (reads Y level 0, pre-overwrite)
    gemm_init<<<MT0, 256, 0, stream>>>(Y, WgtC, out, bsum);

    // 4) z = Y_h @ Wg  IN PLACE on Y, fused with attention-coefficient dots
    gemm_z<<<dim3(MT_ALL, 4), 256, 0, stream>>>(Y, Wgt, a1w, a1b, a2w, a2b, a1o, a2o, Y);

    // 5) per-level pull aggregation (phase-split for cache locality; no atomics)
    pull_agg<<<(N0 + 3) / 4, 256, 0, stream>>>(rp0, srt0, a1o, a2o, Y, out);
    pull_agg<<<(N0 + 3) / 4, 256, 0, stream>>>(rp1, srt1, a1o, a2o, Y, out);
    pull_agg<<<(N0 + 3) / 4, 256, 0, stream>>>(rp2, srt2, a1o, a2o, Y, out);
}